// Round 9
// baseline (1325.914 us; speedup 1.0000x reference)
//
#include <hip/hip_runtime.h>
#include <hip/hip_bf16.h>
#include <hip/hip_fp8.h>
#include <math.h>

#define N_NODES 16384
#define N_EDGES 524288
#define F_IN 128
#define DEG_CAP 96        // Poisson(32): max deg over 16384 nodes ~57; P(>96)~1e-20
#define SENT 16384        // sentinel index -> zeroed row
#define NBLK 512          // 2 blocks/CU: VGPR<=128 (launch_bounds), LDS 20.5KB*2=41KB
#define NTHR 512
#define NTH (NBLK * NTHR) // 262144 threads

typedef __attribute__((ext_vector_type(8))) short short8;
typedef __attribute__((ext_vector_type(4))) float floatx4;
typedef unsigned short ushort_t;
typedef unsigned int uint_t;
typedef unsigned char uchar_t;

__device__ inline float bf2f(ushort_t u) {
    union { uint_t i; float f; } v;
    v.i = ((uint_t)u) << 16;
    return v.f;
}
__device__ inline ushort_t f2bs(float x) {
    __hip_bfloat16 h = __float2bfloat16(x);   // RNE
    return *reinterpret_cast<ushort_t*>(&h);
}
__device__ inline uint_t pack2(float lo, float hi) {
    return (uint_t)f2bs(lo) | ((uint_t)f2bs(hi) << 16);
}
// ---- OCP fp8 e4m3 (gfx950 HW cvt) ----
__device__ inline float f8tof(uint_t b) {
    __hip_fp8_e4m3 h; h.__x = (__hip_fp8_storage_t)(b & 0xff);
    return (float)h;
}
__device__ inline uint_t ftof8(float v) {
    __hip_fp8_e4m3 h(v);                      // RNE, satfinite
    return (uint_t)h.__x;
}

// Generational grid barrier (all NBLK blocks co-resident by construction).
// threadfence before arrival: flush writes to device coherence point (cross-XCD);
// threadfence after release: discard stale local cache lines.
__device__ inline void gridbar(int* __restrict__ bar_cnt,
                               int* __restrict__ bar_gen) {
    __threadfence();
    __syncthreads();
    if (threadIdx.x == 0) {
        int g = __hip_atomic_load(bar_gen, __ATOMIC_RELAXED,
                                  __HIP_MEMORY_SCOPE_AGENT);
        int t = __hip_atomic_fetch_add(bar_cnt, 1, __ATOMIC_ACQ_REL,
                                       __HIP_MEMORY_SCOPE_AGENT);
        if (t == NBLK - 1) {
            __hip_atomic_store(bar_cnt, 0, __ATOMIC_RELAXED,
                               __HIP_MEMORY_SCOPE_AGENT);
            __hip_atomic_fetch_add(bar_gen, 1, __ATOMIC_ACQ_REL,
                                   __HIP_MEMORY_SCOPE_AGENT);
        } else {
            while (__hip_atomic_load(bar_gen, __ATOMIC_ACQUIRE,
                                     __HIP_MEMORY_SCOPE_AGENT) == g)
                __builtin_amdgcn_s_sleep(2);
        }
    }
    __syncthreads();
    __threadfence();
}

// ================= ONE kernel, manual grid barriers, 2 blocks/CU ==========
__global__ __launch_bounds__(512, 4) void mega(
    const int* __restrict__ src, const int* __restrict__ dst,
    const float* __restrict__ features,
    const float* __restrict__ W1, const float* __restrict__ b1,
    const float* __restrict__ W2, const float* __restrict__ b2,
    const float* __restrict__ fc1_w, const float* __restrict__ fc1_b,
    const float* __restrict__ fc2_w, const float* __restrict__ fc2_b,
    int* __restrict__ cur, ushort_t* __restrict__ col,
    float* __restrict__ assignp, float* __restrict__ napart,
    ushort_t* __restrict__ fc1bf, uchar_t* __restrict__ zs8,
    ushort_t* __restrict__ W1t, ushort_t* __restrict__ W2t,
    uchar_t* __restrict__ bufY8, float* __restrict__ gfr,
    int* __restrict__ bar_cnt, int* __restrict__ bar_gen,
    float* __restrict__ out) {
    __shared__ __align__(16) ushort_t Az[16 * 136];
    __shared__ __align__(16) ushort_t Ah[16 * 264];
    __shared__ __align__(8) uint_t scol[768];
    __shared__ float sha[16][65];
    __shared__ float sas0[16], sas1[16];
    __shared__ float red[8][3];

    const int tid = threadIdx.x;
    const int gid = blockIdx.x * NTHR + tid;
    const int lane = tid & 63;
    const int wave = tid >> 6;
    const int m = lane & 15;
    const int quad = lane >> 4;
    const uint_t* colu = (const uint_t*)col;

    // ---- Phase 0: zero cur + gfr ----
    if (gid < N_NODES) cur[gid] = 0;
    else if (gid < N_NODES + 2048) gfr[gid - N_NODES] = 0.f;
    gridbar(bar_cnt, bar_gen);

    // ---- Phase 1: bucket fill (histogram) + weight converts ----
    for (int e = gid; e < N_EDGES; e += NTH) {
        int d = dst[e];
        int pos = atomicAdd(&cur[d], 1);
        if (pos < DEG_CAP) col[d * DEG_CAP + pos] = (ushort_t)src[e];
    }
    if (gid < 114688) {
        int i = gid;
        if (i < 32768) {                 // W1t[n][k] = W1[k][n], 256x128
            int n = i >> 7, k = i & 127;
            W1t[i] = f2bs(W1[k * 256 + n]);
        } else if (i < 98304) {          // W2t[n][k] = W2[k][n], 256x256
            int j = i - 32768;
            int n = j >> 8, k = j & 255;
            W2t[j] = f2bs(W2[k * 256 + n]);
        } else {                         // fc1bf = bf16(fc1_w), 64x256
            int j = i - 98304;
            fc1bf[j] = f2bs(fc1_w[j]);
        }
    }
    gridbar(bar_cnt, bar_gen);

    // ---- Phase 2: zs8 = fp8(dinv*feat); pad col; zero sentinel rows ----
    if (gid < 8) {
        uint4 z4 = {0u, 0u, 0u, 0u};
        *(uint4*)&zs8[(size_t)SENT * 128 + gid * 16] = z4;
    } else if (gid >= 64 && gid < 80) {
        uint4 z4 = {0u, 0u, 0u, 0u};
        *(uint4*)&bufY8[(size_t)SENT * 256 + (gid - 64) * 16] = z4;
    }
    for (int i = gid; i < 524288; i += NTH) {    // 4 floats each
        int node = i >> 5;
        int hl = i & 31;
        int deg = cur[node];
        float d = rsqrtf((float)(deg + 1));
        float4 v = *(const float4*)&features[i * 4];
        uint_t p = ftof8(v.x * d) | (ftof8(v.y * d) << 8) |
                   (ftof8(v.z * d) << 16) | (ftof8(v.w * d) << 24);
        *(uint_t*)&zs8[i * 4] = p;
        if (deg < DEG_CAP) {
            int pad = (16 - (deg & 15)) & 15;
            if (hl < pad) col[node * DEG_CAP + deg + hl] = (ushort_t)SENT;
        }
    }
    gridbar(bar_cnt, bar_gen);

    // ---- Phase 3: agg1 -> gemm1 -> gemm2; 2 tiles of 16 nodes per block ----
    for (int tl = blockIdx.x; tl < N_NODES / 16; tl += NBLK) {
        const int row0 = tl * 16;
        if (tid < 384)
            *(uint2*)&scol[tid * 2] = *(const uint2*)&colu[row0 * 48 + tid * 2];
        __syncthreads();
        {   // Phase A: xa = dinv[n]*(zs[n] + sum_j zs[j])
            const int nl0 = wave * 2, nl1 = wave * 2 + 1;
            const int node0 = row0 + nl0, node1 = row0 + nl1;
            const int foff = lane * 2;
            const int deg0 = cur[node0], deg1 = cur[node1];
            const int nb0 = (min(deg0, DEG_CAP) + 15) >> 4;
            const int nb1 = (min(deg1, DEG_CAP) + 15) >> 4;
            const int nbm = max(nb0, nb1);
            ushort_t s0 = *(const ushort_t*)&zs8[(size_t)node0 * 128 + foff];
            ushort_t s1 = *(const ushort_t*)&zs8[(size_t)node1 * 128 + foff];
            float a00 = f8tof(s0), a01 = f8tof(s0 >> 8);
            float a10 = f8tof(s1), a11 = f8tof(s1 >> 8);
            for (int tb = 0; tb < nbm; ++tb) {
                const bool p0 = tb < nb0, p1 = tb < nb1;
                uint_t w0[8], w1[8];
                if (p0) {
                    #pragma unroll
                    for (int k = 0; k < 8; ++k) w0[k] = scol[nl0 * 48 + tb * 8 + k];
                }
                if (p1) {
                    #pragma unroll
                    for (int k = 0; k < 8; ++k) w1[k] = scol[nl1 * 48 + tb * 8 + k];
                }
                ushort_t g0[16], g1[16];
                if (p0) {
                    #pragma unroll
                    for (int k = 0; k < 8; ++k) {
                        int j0 = w0[k] & 0xffff, j1 = w0[k] >> 16;
                        g0[2 * k]     = *(const ushort_t*)&zs8[(size_t)j0 * 128 + foff];
                        g0[2 * k + 1] = *(const ushort_t*)&zs8[(size_t)j1 * 128 + foff];
                    }
                }
                if (p1) {
                    #pragma unroll
                    for (int k = 0; k < 8; ++k) {
                        int j0 = w1[k] & 0xffff, j1 = w1[k] >> 16;
                        g1[2 * k]     = *(const ushort_t*)&zs8[(size_t)j0 * 128 + foff];
                        g1[2 * k + 1] = *(const ushort_t*)&zs8[(size_t)j1 * 128 + foff];
                    }
                }
                if (p0) {
                    #pragma unroll
                    for (int q = 0; q < 16; ++q) {
                        a00 += f8tof(g0[q]); a01 += f8tof(g0[q] >> 8);
                    }
                }
                if (p1) {
                    #pragma unroll
                    for (int q = 0; q < 16; ++q) {
                        a10 += f8tof(g1[q]); a11 += f8tof(g1[q] >> 8);
                    }
                }
            }
            float dn0 = rsqrtf((float)(deg0 + 1));
            float dn1 = rsqrtf((float)(deg1 + 1));
            *(uint_t*)&Az[nl0 * 136 + foff] = pack2(a00 * dn0, a01 * dn0);
            *(uint_t*)&Az[nl1 * 136 + foff] = pack2(a10 * dn1, a11 * dn1);
        }
        __syncthreads();
        // Phase B: h1 = relu(Az @ W1t^T + b1), K=128; 32 cols/wave
        const int wcol0 = wave * 32;
        floatx4 acc[2];
        const floatx4 zero4 = {0.f, 0.f, 0.f, 0.f};
        acc[0] = zero4; acc[1] = zero4;
        #pragma unroll
        for (int k0 = 0; k0 < 128; k0 += 32) {
            short8 a = *(const short8*)&Az[m * 136 + k0 + quad * 8];
            #pragma unroll
            for (int j = 0; j < 2; ++j) {
                short8 bb = *(const short8*)
                    &W1t[(size_t)(wcol0 + j * 16 + m) * 128 + k0 + quad * 8];
                acc[j] = __builtin_amdgcn_mfma_f32_16x16x32_bf16(a, bb, acc[j], 0, 0, 0);
            }
        }
        #pragma unroll
        for (int j = 0; j < 2; ++j) {
            int cg_ = wcol0 + j * 16 + m;
            float bv = b1[cg_];
            #pragma unroll
            for (int r = 0; r < 4; ++r) {
                float v = fmaxf(acc[j][r] + bv, 0.0f);
                Ah[(quad * 4 + r) * 264 + cg_] = f2bs(v);
            }
        }
        __syncthreads();
        // Phase C: ys = (Ah @ W2t^T)*dinv -> bufY8 (fp8), K=256
        acc[0] = zero4; acc[1] = zero4;
        #pragma unroll
        for (int k0 = 0; k0 < 256; k0 += 32) {
            short8 a = *(const short8*)&Ah[m * 264 + k0 + quad * 8];
            #pragma unroll
            for (int j = 0; j < 2; ++j) {
                short8 bb = *(const short8*)
                    &W2t[(size_t)(wcol0 + j * 16 + m) * 256 + k0 + quad * 8];
                acc[j] = __builtin_amdgcn_mfma_f32_16x16x32_bf16(a, bb, acc[j], 0, 0, 0);
            }
        }
        float rs4[4];
        #pragma unroll
        for (int r = 0; r < 4; ++r)
            rs4[r] = rsqrtf((float)(cur[row0 + quad * 4 + r] + 1));
        #pragma unroll
        for (int j = 0; j < 2; ++j) {
            int cg_ = wcol0 + j * 16 + m;
            #pragma unroll
            for (int r = 0; r < 4; ++r)
                bufY8[(size_t)(row0 + quad * 4 + r) * 256 + cg_] =
                    (uchar_t)ftof8(acc[j][r] * rs4[r]);
        }
        __syncthreads();
    }
    gridbar(bar_cnt, bar_gen);

    // ---- Phase 4: agg2 -> fc1 -> tanh -> fc2 -> softmax -> gf pool ----
    for (int tl = blockIdx.x; tl < N_NODES / 16; tl += NBLK) {
        const int row0 = tl * 16;
        if (tid < 384)
            *(uint2*)&scol[tid * 2] = *(const uint2*)&colu[row0 * 48 + tid * 2];
        __syncthreads();
        {   // Phase A: h2 = dinv[n]*(y[n] + sum_j y[j]) + b2
            const int nl0 = wave * 2, nl1 = wave * 2 + 1;
            const int node0 = row0 + nl0, node1 = row0 + nl1;
            const int foff = lane * 4;
            const int deg0 = cur[node0], deg1 = cur[node1];
            const int nb0 = (min(deg0, DEG_CAP) + 15) >> 4;
            const int nb1 = (min(deg1, DEG_CAP) + 15) >> 4;
            const int nbm = max(nb0, nb1);
            uint_t sv0 = *(const uint_t*)&bufY8[(size_t)node0 * 256 + foff];
            uint_t sv1 = *(const uint_t*)&bufY8[(size_t)node1 * 256 + foff];
            float a00 = f8tof(sv0),       a01 = f8tof(sv0 >> 8);
            float a02 = f8tof(sv0 >> 16), a03 = f8tof(sv0 >> 24);
            float a10 = f8tof(sv1),       a11 = f8tof(sv1 >> 8);
            float a12 = f8tof(sv1 >> 16), a13 = f8tof(sv1 >> 24);
            for (int tb = 0; tb < nbm; ++tb) {
                const bool p0 = tb < nb0, p1 = tb < nb1;
                uint_t w0[8], w1[8];
                if (p0) {
                    #pragma unroll
                    for (int k = 0; k < 8; ++k) w0[k] = scol[nl0 * 48 + tb * 8 + k];
                }
                if (p1) {
                    #pragma unroll
                    for (int k = 0; k < 8; ++k) w1[k] = scol[nl1 * 48 + tb * 8 + k];
                }
                uint_t g0[16], g1[16];
                if (p0) {
                    #pragma unroll
                    for (int k = 0; k < 8; ++k) {
                        int j0 = w0[k] & 0xffff, j1 = w0[k] >> 16;
                        g0[2 * k]     = *(const uint_t*)&bufY8[(size_t)j0 * 256 + foff];
                        g0[2 * k + 1] = *(const uint_t*)&bufY8[(size_t)j1 * 256 + foff];
                    }
                }
                if (p1) {
                    #pragma unroll
                    for (int k = 0; k < 8; ++k) {
                        int j0 = w1[k] & 0xffff, j1 = w1[k] >> 16;
                        g1[2 * k]     = *(const uint_t*)&bufY8[(size_t)j0 * 256 + foff];
                        g1[2 * k + 1] = *(const uint_t*)&bufY8[(size_t)j1 * 256 + foff];
                    }
                }
                if (p0) {
                    #pragma unroll
                    for (int q = 0; q < 16; ++q) {
                        a00 += f8tof(g0[q]);       a01 += f8tof(g0[q] >> 8);
                        a02 += f8tof(g0[q] >> 16); a03 += f8tof(g0[q] >> 24);
                    }
                }
                if (p1) {
                    #pragma unroll
                    for (int q = 0; q < 16; ++q) {
                        a10 += f8tof(g1[q]);       a11 += f8tof(g1[q] >> 8);
                        a12 += f8tof(g1[q] >> 16); a13 += f8tof(g1[q] >> 24);
                    }
                }
            }
            float di0 = rsqrtf((float)(deg0 + 1));
            float di1 = rsqrtf((float)(deg1 + 1));
            float4 bv = *(const float4*)&b2[foff];
            uint2 pk;
            pk.x = pack2(a00 * di0 + bv.x, a01 * di0 + bv.y);
            pk.y = pack2(a02 * di0 + bv.z, a03 * di0 + bv.w);
            *(uint2*)&Ah[nl0 * 264 + foff] = pk;
            pk.x = pack2(a10 * di1 + bv.x, a11 * di1 + bv.y);
            pk.y = pack2(a12 * di1 + bv.z, a13 * di1 + bv.w);
            *(uint2*)&Ah[nl1 * 264 + foff] = pk;
        }
        __syncthreads();
        // Phase B: a1 = tanh(Ah @ fc1bf^T + fc1_b), K=256 (waves 0-3)
        if (wave < 4) {
            floatx4 acc = {0.f, 0.f, 0.f, 0.f};
            #pragma unroll
            for (int k0 = 0; k0 < 256; k0 += 32) {
                short8 a = *(const short8*)&Ah[m * 264 + k0 + quad * 8];
                short8 bb = *(const short8*)
                    &fc1bf[(size_t)(wave * 16 + m) * 256 + k0 + quad * 8];
                acc = __builtin_amdgcn_mfma_f32_16x16x32_bf16(a, bb, acc, 0, 0, 0);
            }
            int cg_ = wave * 16 + m;
            float bv = fc1_b[cg_];
            #pragma unroll
            for (int r = 0; r < 4; ++r)
                sha[quad * 4 + r][cg_] = tanhf(acc[r] + bv);
        }
        __syncthreads();
        // fc2 + softmax (one thread per node)
        if (tid < 16) {
            float p0 = fc2_b[0], p1 = fc2_b[1];
            #pragma unroll 8
            for (int t = 0; t < 64; ++t) {
                float a = sha[tid][t];
                p0 += a * fc2_w[t];
                p1 += a * fc2_w[64 + t];
            }
            float mx = fmaxf(p0, p1);
            float e0 = expf(p0 - mx), e1 = expf(p1 - mx);
            float inv = 1.0f / (e0 + e1);
            assignp[row0 + tid] = e0 * inv;
            sas0[tid] = e0 * inv; sas1[tid] = e1 * inv;
        }
        __syncthreads();
        // gf pooling; 512 thr = (feature, which-half)
        {
            const int f = tid & 255;
            const int which = tid >> 8;
            const float* sv = which ? sas1 : sas0;
            float acc = 0.f;
            #pragma unroll
            for (int i = 0; i < 16; ++i)
                acc += sv[i] * bf2f(Ah[i * 264 + f]);
            float* gfc = gfr + (tl & 3) * 512;
            atomicAdd(&gfc[which * 256 + f], acc);
        }
        __syncthreads();
    }
    gridbar(bar_cnt, bar_gen);

    // ---- Phase 5: newadj partials (p1 = 1-p0 identity), 2 edges/thread ----
    {
        int g2 = gid * 2;
        int2 sv = *(const int2*)&src[g2];
        int2 dv = *(const int2*)&dst[g2];
        float s0 = assignp[sv.x], s1 = assignp[sv.y];
        float d0 = assignp[dv.x], d1 = assignp[dv.y];
        float ss = s0 + s1;
        float sd = d0 + d1;
        float ssd = s0 * d0 + s1 * d1;
        #pragma unroll
        for (int off = 32; off; off >>= 1) {
            ss += __shfl_down(ss, off);
            sd += __shfl_down(sd, off);
            ssd += __shfl_down(ssd, off);
        }
        if (lane == 0) {
            red[wave][0] = ssd; red[wave][1] = ss; red[wave][2] = sd;
        }
        __syncthreads();
        if (tid < 3) {
            float v = 0.f;
            #pragma unroll
            for (int w = 0; w < 8; ++w) v += red[w][tid];
            napart[blockIdx.x * 4 + tid] = v;
        }
    }
    gridbar(bar_cnt, bar_gen);

    // ---- Phase 6: block 0 finalizes all outputs ----
    if (blockIdx.x == 0) {
        float p0 = napart[tid * 4], p1 = napart[tid * 4 + 1],
              p2 = napart[tid * 4 + 2];
        #pragma unroll
        for (int off = 32; off; off >>= 1) {
            p0 += __shfl_down(p0, off);
            p1 += __shfl_down(p1, off);
            p2 += __shfl_down(p2, off);
        }
        if (lane == 0) {
            red[wave][0] = p0; red[wave][1] = p1; red[wave][2] = p2;
        }
        __syncthreads();
        if (tid < 256) {
            float g0 = gfr[tid] + gfr[512 + tid] + gfr[1024 + tid] + gfr[1536 + tid];
            float g1 = gfr[256 + tid] + gfr[768 + tid] + gfr[1280 + tid] + gfr[1792 + tid];
            out[tid] = 0.5f * (g0 + g1);
            out[256 + tid] = fminf(fmaxf(g0, -100.f), 100.f);
            out[512 + tid] = fminf(fmaxf(g1, -100.f), 100.f);
        }
        if (tid == 0) {
            float Ssd = 0.f, Ss = 0.f, Sd = 0.f;
            #pragma unroll
            for (int w = 0; w < 8; ++w) {
                Ssd += red[w][0]; Ss += red[w][1]; Sd += red[w][2];
            }
            float n00 = Ssd;
            float n01 = Ss - Ssd;
            float n10 = Sd - Ssd;
            float n11 = (float)N_EDGES - Ss - Sd + Ssd;
            float den0 = fmaxf(fabsf(n00) + fabsf(n01), 1e-12f);
            float den1 = fmaxf(fabsf(n10) + fabsf(n11), 1e-12f);
            float x0 = n00 / den0 - 1.0f;
            float x1 = n11 / den1 - 1.0f;
            out[768] = 0.5f * (x0 * x0 + x1 * x1);
        }
    }
}

// ---------------- launch ----------------

extern "C" void kernel_launch(void* const* d_in, const int* in_sizes, int n_in,
                              void* d_out, int out_size, void* d_ws, size_t ws_size,
                              hipStream_t stream) {
    const float* features = (const float*)d_in[0];
    const int* edges = (const int*)d_in[1];
    const int* src = edges;
    const int* dst = edges + N_EDGES;
    const float* W1 = (const float*)d_in[2];
    const float* b1 = (const float*)d_in[3];
    const float* W2 = (const float*)d_in[4];
    const float* b2 = (const float*)d_in[5];
    const float* fc1_w = (const float*)d_in[6];
    const float* fc1_b = (const float*)d_in[7];
    const float* fc2_w = (const float*)d_in[8];
    const float* fc2_b = (const float*)d_in[9];
    float* out = (float*)d_out;

    char* ws = (char*)d_ws;
    auto carve = [&](size_t bytes) {
        void* q = (void*)ws;
        ws += (bytes + 255) & ~(size_t)255;
        return q;
    };
    int* bar = (int*)carve(256);                     // bar_cnt, bar_gen (memset)
    int* cur = (int*)carve(N_NODES * 4);             // zeroed in-kernel phase 0
    float* gfr = (float*)carve(4 * 512 * 4);         // zeroed in-kernel phase 0
    ushort_t* col = (ushort_t*)carve((size_t)N_NODES * DEG_CAP * 2);  // 3.1 MB
    float* assignp = (float*)carve(N_NODES * 4);
    float* napart = (float*)carve(NBLK * 4 * 4);
    ushort_t* fc1bf = (ushort_t*)carve(64 * 256 * 2);
    uchar_t* zs8 = (uchar_t*)carve((size_t)(N_NODES + 1) * F_IN);     // 2.1 MB
    ushort_t* W1t = (ushort_t*)carve(256 * 128 * 2);
    ushort_t* W2t = (ushort_t*)carve(256 * 256 * 2);
    uchar_t* bufY8 = (uchar_t*)carve((size_t)(N_NODES + 1) * 256);    // 4.2 MB

    int* bar_cnt = bar;
    int* bar_gen = bar + 1;

    hipMemsetAsync(bar, 0, 256, stream);

    mega<<<NBLK, NTHR, 0, stream>>>(
        src, dst, features, W1, b1, W2, b2, fc1_w, fc1_b, fc2_w, fc2_b,
        cur, col, assignp, napart, fc1bf, zs8, W1t, W2t, bufY8, gfr,
        bar_cnt, bar_gen, out);
}

// Round 10
// 209.207 us; speedup vs baseline: 6.3378x; 6.3378x over previous
//
#include <hip/hip_runtime.h>
#include <hip/hip_bf16.h>
#include <hip/hip_fp8.h>
#include <math.h>

#define N_NODES 16384
#define N_EDGES 524288
#define F_IN 128
#define DEG_CAP 96        // Poisson(32): max deg over 16384 nodes ~57; P(>96)~1e-20
#define SENT 16384        // sentinel index -> zeroed row
#define GF_GRID 256

typedef __attribute__((ext_vector_type(8))) short short8;
typedef __attribute__((ext_vector_type(4))) float floatx4;
typedef unsigned short ushort_t;
typedef unsigned int uint_t;
typedef unsigned char uchar_t;

__device__ inline float bf2f(ushort_t u) {
    union { uint_t i; float f; } v;
    v.i = ((uint_t)u) << 16;
    return v.f;
}
__device__ inline ushort_t f2bs(float x) {
    __hip_bfloat16 h = __float2bfloat16(x);   // RNE
    return *reinterpret_cast<ushort_t*>(&h);
}
__device__ inline uint_t pack2(float lo, float hi) {
    return (uint_t)f2bs(lo) | ((uint_t)f2bs(hi) << 16);
}
// ---- OCP fp8 e4m3 (gfx950 HW cvt) ----
__device__ inline float f8tof(uint_t b) {
    __hip_fp8_e4m3 h; h.__x = (__hip_fp8_storage_t)(b & 0xff);
    return (float)h;
}
__device__ inline uint_t ftof8(float v) {
    __hip_fp8_e4m3 h(v);                      // RNE, satfinite
    return (uint_t)h.__x;
}

// ------- dual bucket fill (dst AND src histograms) + weight converts -------
__global__ __launch_bounds__(256) void prep_fill(
    const int* __restrict__ src, const int* __restrict__ dst,
    const float* __restrict__ W1, const float* __restrict__ W2,
    const float* __restrict__ fc1_w,
    int* __restrict__ cur, int* __restrict__ cur2,
    ushort_t* __restrict__ col, ushort_t* __restrict__ col2,
    ushort_t* __restrict__ W1t, ushort_t* __restrict__ W2t,
    ushort_t* __restrict__ fc1bf) {
    int b = blockIdx.x, t = threadIdx.x;
    if (b < 2048) {                          // in-edges: bucket by dst
        int e = b * 256 + t;
        int d = dst[e];
        int pos = atomicAdd(&cur[d], 1);
        if (pos < DEG_CAP) col[d * DEG_CAP + pos] = (ushort_t)src[e];
    } else if (b < 4096) {                   // out-edges: bucket by src
        int e = (b - 2048) * 256 + t;
        int s = src[e];
        int pos = atomicAdd(&cur2[s], 1);
        if (pos < DEG_CAP) col2[s * DEG_CAP + pos] = (ushort_t)dst[e];
    } else if (b < 4224) {
        int idx = (b - 4096) * 256 + t;      // W1t[n][k] = W1[k][n], 256x128
        int n = idx >> 7, k = idx & 127;
        W1t[idx] = f2bs(W1[k * 256 + n]);
    } else if (b < 4480) {
        int idx = (b - 4224) * 256 + t;      // W2t[n][k] = W2[k][n], 256x256
        int n = idx >> 8, k = idx & 255;
        W2t[idx] = f2bs(W2[k * 256 + n]);
    } else {
        int idx = (b - 4480) * 256 + t;      // fc1bf = bf16(fc1_w), 64x256
        fc1bf[idx] = f2bs(fc1_w[idx]);
    }
}

// ------- zs8 = fp8(dinv*feat); pad BOTH bucket sets; sentinels; c1f -------
__global__ __launch_bounds__(256) void scale_feat(
    const float* __restrict__ features, const int* __restrict__ cnt,
    const int* __restrict__ cnt2,
    uchar_t* __restrict__ zs8, uchar_t* __restrict__ ts8,
    ushort_t* __restrict__ col, ushort_t* __restrict__ col2,
    const float* __restrict__ fc1_w, const float* __restrict__ b2,
    const float* __restrict__ fc1_b, float* __restrict__ c1f,
    float* __restrict__ packf) {
    int b = blockIdx.x, t = threadIdx.x;
    if (b == 2048) {
        if (t < 64) {                       // c1[t] = fc1_b[t] + fc1_w[t,:]·b2
            float acc = fc1_b[t];
            #pragma unroll 4
            for (int k = 0; k < 256; k += 4) {
                float4 w = *(const float4*)&fc1_w[t * 256 + k];
                float4 bb = *(const float4*)&b2[k];
                acc += w.x * bb.x + w.y * bb.y + w.z * bb.z + w.w * bb.w;
            }
            c1f[t] = acc;
        } else if (t < 72) {                // zs8 sentinel row: 128 B
            uint4 z4 = {0u, 0u, 0u, 0u};
            *(uint4*)&zs8[(size_t)SENT * 128 + (t - 64) * 16] = z4;
        } else if (t < 76) {                // ts8 sentinel row: 64 B
            uint4 z4 = {0u, 0u, 0u, 0u};
            *(uint4*)&ts8[(size_t)SENT * 64 + (t - 72) * 16] = z4;
        } else if (t < 80) {                // packf sentinel row: 4 floats
            packf[SENT * 4 + (t - 76)] = 0.f;
        }
        return;
    }
    int gid = b * 256 + t;                  // 0..524287, 4 floats each
    int node = gid >> 5;
    int hl = gid & 31;
    int deg = cnt[node];
    float d = rsqrtf((float)(deg + 1));
    float4 v = *(const float4*)&features[gid * 4];
    uint_t p = ftof8(v.x * d) | (ftof8(v.y * d) << 8) |
               (ftof8(v.z * d) << 16) | (ftof8(v.w * d) << 24);
    *(uint_t*)&zs8[gid * 4] = p;
    if (deg < DEG_CAP) {                    // pad in-bucket to x16
        int pad = (16 - (deg & 15)) & 15;
        if (hl < pad) col[node * DEG_CAP + deg + hl] = (ushort_t)SENT;
    }
    int odeg = cnt2[node];
    if (odeg < DEG_CAP) {                   // pad out-bucket to x16 (thr 16..31)
        int pad2 = (16 - (odeg & 15)) & 15;
        if (hl >= 16 && hl - 16 < pad2)
            col2[node * DEG_CAP + odeg + (hl - 16)] = (ushort_t)SENT;
    }
}

// ===== agg1 -> gemm1 -> gemm2 -> ts = ys@fc1^T, 16 nodes/block (R8-proven) ==
__global__ __launch_bounds__(512, 4) void fused_layer1(
    const uchar_t* __restrict__ zs8, const int* __restrict__ cnt,
    const ushort_t* __restrict__ col, const float* __restrict__ b1,
    const ushort_t* __restrict__ W1t, const ushort_t* __restrict__ W2t,
    const ushort_t* __restrict__ fc1bf,
    uchar_t* __restrict__ bufY8, uchar_t* __restrict__ ts8) {
    __shared__ __align__(16) ushort_t Az[16 * 136];
    __shared__ __align__(16) ushort_t Ah[16 * 264];
    __shared__ __align__(8) uint_t scol[768];
    const int tid = threadIdx.x;
    const int lane = tid & 63;
    const int wave = tid >> 6;
    const int m = lane & 15;
    const int quad = lane >> 4;
    const int row0 = blockIdx.x * 16;
    const uint_t* colu = (const uint_t*)col;

    if (tid < 384)
        *(uint2*)&scol[tid * 2] = *(const uint2*)&colu[row0 * 48 + tid * 2];
    __syncthreads();
    {   // Phase A: xa = dinv[n]*(zs[n] + sum_j zs[j])
        const int nl0 = wave * 2, nl1 = wave * 2 + 1;
        const int node0 = row0 + nl0, node1 = row0 + nl1;
        const int foff = lane * 2;
        const int deg0 = cnt[node0], deg1 = cnt[node1];
        const int nb0 = (min(deg0, DEG_CAP) + 15) >> 4;
        const int nb1 = (min(deg1, DEG_CAP) + 15) >> 4;
        const int nbm = max(nb0, nb1);
        ushort_t s0 = *(const ushort_t*)&zs8[(size_t)node0 * 128 + foff];
        ushort_t s1 = *(const ushort_t*)&zs8[(size_t)node1 * 128 + foff];
        float a00 = f8tof(s0), a01 = f8tof(s0 >> 8);
        float a10 = f8tof(s1), a11 = f8tof(s1 >> 8);
        for (int tb = 0; tb < nbm; ++tb) {
            const bool p0 = tb < nb0, p1 = tb < nb1;
            uint_t w0[8], w1[8];
            if (p0) {
                #pragma unroll
                for (int k = 0; k < 8; ++k) w0[k] = scol[nl0 * 48 + tb * 8 + k];
            }
            if (p1) {
                #pragma unroll
                for (int k = 0; k < 8; ++k) w1[k] = scol[nl1 * 48 + tb * 8 + k];
            }
            ushort_t g0[16], g1[16];
            if (p0) {
                #pragma unroll
                for (int k = 0; k < 8; ++k) {
                    int j0 = w0[k] & 0xffff, j1 = w0[k] >> 16;
                    g0[2 * k]     = *(const ushort_t*)&zs8[(size_t)j0 * 128 + foff];
                    g0[2 * k + 1] = *(const ushort_t*)&zs8[(size_t)j1 * 128 + foff];
                }
            }
            if (p1) {
                #pragma unroll
                for (int k = 0; k < 8; ++k) {
                    int j0 = w1[k] & 0xffff, j1 = w1[k] >> 16;
                    g1[2 * k]     = *(const ushort_t*)&zs8[(size_t)j0 * 128 + foff];
                    g1[2 * k + 1] = *(const ushort_t*)&zs8[(size_t)j1 * 128 + foff];
                }
            }
            if (p0) {
                #pragma unroll
                for (int q = 0; q < 16; ++q) {
                    a00 += f8tof(g0[q]); a01 += f8tof(g0[q] >> 8);
                }
            }
            if (p1) {
                #pragma unroll
                for (int q = 0; q < 16; ++q) {
                    a10 += f8tof(g1[q]); a11 += f8tof(g1[q] >> 8);
                }
            }
        }
        float dn0 = rsqrtf((float)(deg0 + 1));
        float dn1 = rsqrtf((float)(deg1 + 1));
        *(uint_t*)&Az[nl0 * 136 + foff] = pack2(a00 * dn0, a01 * dn0);
        *(uint_t*)&Az[nl1 * 136 + foff] = pack2(a10 * dn1, a11 * dn1);
    }
    __syncthreads();
    // Phase B: h1 = relu(Az @ W1t^T + b1), K=128; 32 cols/wave
    const int wcol0 = wave * 32;
    floatx4 acc[2];
    const floatx4 zero4 = {0.f, 0.f, 0.f, 0.f};
    acc[0] = zero4; acc[1] = zero4;
    #pragma unroll
    for (int k0 = 0; k0 < 128; k0 += 32) {
        short8 a = *(const short8*)&Az[m * 136 + k0 + quad * 8];
        #pragma unroll
        for (int j = 0; j < 2; ++j) {
            short8 bb = *(const short8*)
                &W1t[(size_t)(wcol0 + j * 16 + m) * 128 + k0 + quad * 8];
            acc[j] = __builtin_amdgcn_mfma_f32_16x16x32_bf16(a, bb, acc[j], 0, 0, 0);
        }
    }
    #pragma unroll
    for (int j = 0; j < 2; ++j) {
        int cg_ = wcol0 + j * 16 + m;
        float bv = b1[cg_];
        #pragma unroll
        for (int r = 0; r < 4; ++r) {
            float v = fmaxf(acc[j][r] + bv, 0.0f);
            Ah[(quad * 4 + r) * 264 + cg_] = f2bs(v);
        }
    }
    __syncthreads();
    // Phase C: ys = (Ah @ W2t^T)*dinv -> bufY8 (fp8) + Ah (bf16, for ts)
    acc[0] = zero4; acc[1] = zero4;
    #pragma unroll
    for (int k0 = 0; k0 < 256; k0 += 32) {
        short8 a = *(const short8*)&Ah[m * 264 + k0 + quad * 8];
        #pragma unroll
        for (int j = 0; j < 2; ++j) {
            short8 bb = *(const short8*)
                &W2t[(size_t)(wcol0 + j * 16 + m) * 256 + k0 + quad * 8];
            acc[j] = __builtin_amdgcn_mfma_f32_16x16x32_bf16(a, bb, acc[j], 0, 0, 0);
        }
    }
    float rs4[4];
    #pragma unroll
    for (int r = 0; r < 4; ++r)
        rs4[r] = rsqrtf((float)(cnt[row0 + quad * 4 + r] + 1));
    __syncthreads();              // all waves done READING Ah (h1)
    #pragma unroll
    for (int j = 0; j < 2; ++j) {
        int cg_ = wcol0 + j * 16 + m;
        #pragma unroll
        for (int r = 0; r < 4; ++r) {
            float ys = acc[j][r] * rs4[r];
            bufY8[(size_t)(row0 + quad * 4 + r) * 256 + cg_] = (uchar_t)ftof8(ys);
            Ah[(quad * 4 + r) * 264 + cg_] = f2bs(ys);
        }
    }
    __syncthreads();
    // Phase D: ts(16x64) = ysLDS @ fc1bf^T, K=256 (waves 0-3) -> ts8 fp8
    if (wave < 4) {
        floatx4 at = zero4;
        #pragma unroll
        for (int k0 = 0; k0 < 256; k0 += 32) {
            short8 a = *(const short8*)&Ah[m * 264 + k0 + quad * 8];
            short8 bb = *(const short8*)
                &fc1bf[(size_t)(wave * 16 + m) * 256 + k0 + quad * 8];
            at = __builtin_amdgcn_mfma_f32_16x16x32_bf16(a, bb, at, 0, 0, 0);
        }
        int cg_ = wave * 16 + m;
        #pragma unroll
        for (int r = 0; r < 4; ++r)
            ts8[(size_t)(row0 + quad * 4 + r) * 64 + cg_] = (uchar_t)ftof8(at[r]);
    }
}

// ===== agg2 over ts8 (64B rows) -> tanh -> fc2 -> softmax -> packf =====
__global__ __launch_bounds__(512, 4) void assign2(
    const uchar_t* __restrict__ ts8, const int* __restrict__ cnt,
    const ushort_t* __restrict__ col, const float* __restrict__ c1f,
    const float* __restrict__ fc2_w, const float* __restrict__ fc2_b,
    float* __restrict__ packf) {
    __shared__ __align__(8) uint_t scol[768];
    const int tid = threadIdx.x;
    const int lane = tid & 63;
    const int wave = tid >> 6;
    const int half = lane >> 5;
    const int il = lane & 31;
    const int row0 = blockIdx.x * 16;
    const uint_t* colu = (const uint_t*)col;

    if (tid < 384)
        *(uint2*)&scol[tid * 2] = *(const uint2*)&colu[row0 * 48 + tid * 2];
    __syncthreads();

    const int nl = wave * 2 + half;
    const int node = row0 + nl;
    const int foff = il * 2;                  // 2 fp8 per lane
    const int deg = cnt[node];
    const int nb = (min(deg, DEG_CAP) + 15) >> 4;
    ushort_t sv = *(const ushort_t*)&ts8[(size_t)node * 64 + foff];
    float a0 = f8tof(sv), a1 = f8tof(sv >> 8);
    for (int tb = 0; tb < nb; ++tb) {
        uint_t w[8];
        #pragma unroll
        for (int k = 0; k < 8; ++k) w[k] = scol[nl * 48 + tb * 8 + k];
        ushort_t g[16];
        #pragma unroll
        for (int k = 0; k < 8; ++k) {
            int j0 = w[k] & 0xffff, j1 = w[k] >> 16;
            g[2 * k]     = *(const ushort_t*)&ts8[(size_t)j0 * 64 + foff];
            g[2 * k + 1] = *(const ushort_t*)&ts8[(size_t)j1 * 64 + foff];
        }
        #pragma unroll
        for (int q = 0; q < 16; ++q) {
            a0 += f8tof(g[q]); a1 += f8tof(g[q] >> 8);
        }
    }
    float dinv = rsqrtf((float)(deg + 1));
    float t0 = tanhf(dinv * a0 + c1f[foff]);
    float t1 = tanhf(dinv * a1 + c1f[foff + 1]);
    float part0 = t0 * fc2_w[foff] + t1 * fc2_w[foff + 1];
    float part1 = t0 * fc2_w[64 + foff] + t1 * fc2_w[64 + foff + 1];
    #pragma unroll
    for (int mask = 1; mask < 32; mask <<= 1) {
        part0 += __shfl_xor(part0, mask);
        part1 += __shfl_xor(part1, mask);
    }
    if (il == 0) {
        float l0 = fc2_b[0] + part0, l1 = fc2_b[1] + part1;
        float mx = fmaxf(l0, l1);
        float e0 = expf(l0 - mx), e1 = expf(l1 - mx);
        float p0v = e0 / (e0 + e1);
        float4 pk;
        pk.x = p0v; pk.y = p0v * dinv; pk.z = dinv; pk.w = 0.f;
        *(float4*)&packf[node * 4] = pk;
    }
}

// ===== gf: reverse-bucket q gather + stream bufY8 + newadj + finalize =====
// gf_c = sum_n (w_c[n] + q_c[n])*ys[n] + P_c*b2, q_c[j] = sum_{d in col2[j]} w_c[d]
// newadj: Ss = sum p0*odeg, Sd = sum p0*ideg, Ssd = sum_n p0[n]*sum_{j in col[n]} p0[j]
__global__ __launch_bounds__(256) void gf_fin(
    const uchar_t* __restrict__ bufY8, const float* __restrict__ packf,
    const int* __restrict__ cnt, const int* __restrict__ cnt2,
    const ushort_t* __restrict__ col, const ushort_t* __restrict__ col2,
    float* __restrict__ napart, float* __restrict__ gfr,
    const float* __restrict__ b2, int* __restrict__ cntt,
    float* __restrict__ out) {
    __shared__ float sq0[64], sq1[64];
    __shared__ float red[4][4];
    __shared__ float sred[4][512];
    __shared__ float fin[4];
    __shared__ int sticket;
    const int tid = threadIdx.x;
    const int lane = tid & 63;
    const int wave = tid >> 6;
    const int nb0 = blockIdx.x * 64;
    const int li = lane & 15;
    const int part = lane >> 4;               // 4 parts per node
    const int ni = wave * 16 + li;            // 0..63
    const int node = nb0 + ni;

    // ---- Phase 1: per-node q + na partials (4 lanes per node, strided) ----
    const int ideg = cnt[node], odeg = cnt2[node];
    const int ic16 = ((min(ideg, DEG_CAP) + 15) >> 4) << 4;
    const int oc16 = ((min(odeg, DEG_CAP) + 15) >> 4) << 4;
    float pin = 0.f, q0p = 0.f, q1p = 0.f;
    for (int k = part; k < ic16; k += 4) {
        int j = col[node * DEG_CAP + k];
        pin += packf[j * 4];
    }
    for (int k = part; k < oc16; k += 4) {
        int j = col2[node * DEG_CAP + k];
        float4 pj = *(const float4*)&packf[j * 4];
        q0p += pj.y;
        q1p += pj.z - pj.y;
    }
    #pragma unroll
    for (int mask = 16; mask < 64; mask <<= 1) {
        pin += __shfl_xor(pin, mask);
        q0p += __shfl_xor(q0p, mask);
        q1p += __shfl_xor(q1p, mask);
    }
    if (part == 0) { sq0[ni] = q0p; sq1[ni] = q1p; }
    float p0n = (part == 0) ? packf[node * 4] : 0.f;
    float vssd = p0n * pin;
    float vss = p0n * (float)odeg;
    float vsd = p0n * (float)ideg;
    float vp = p0n;
    #pragma unroll
    for (int off = 32; off; off >>= 1) {
        vssd += __shfl_down(vssd, off);
        vss += __shfl_down(vss, off);
        vsd += __shfl_down(vsd, off);
        vp += __shfl_down(vp, off);
    }
    if (lane == 0) {
        red[wave][0] = vssd; red[wave][1] = vss;
        red[wave][2] = vsd;  red[wave][3] = vp;
    }
    __syncthreads();
    if (tid < 4) {
        float v = red[0][tid] + red[1][tid] + red[2][tid] + red[3][tid];
        __hip_atomic_store(&napart[blockIdx.x * 4 + tid], v, __ATOMIC_RELEASE,
                           __HIP_MEMORY_SCOPE_AGENT);
    }

    // ---- Phase 2: stream bufY8 with weights (w + q) ----
    float f0[4] = {0.f, 0.f, 0.f, 0.f};
    float f1[4] = {0.f, 0.f, 0.f, 0.f};
    for (int n = wave; n < 64; n += 4) {
        int nd = nb0 + n;
        float4 pk = *(const float4*)&packf[nd * 4];
        float w0 = pk.y + sq0[n];
        float w1 = (pk.z - pk.y) + sq1[n];
        uint_t v = *(const uint_t*)&bufY8[(size_t)nd * 256 + lane * 4];
        #pragma unroll
        for (int i = 0; i < 4; ++i) {
            float x = f8tof(v >> (8 * i));
            f0[i] += w0 * x;
            f1[i] += w1 * x;
        }
    }
    #pragma unroll
    for (int i = 0; i < 4; ++i) {
        sred[wave][lane * 4 + i] = f0[i];
        sred[wave][256 + lane * 4 + i] = f1[i];
    }
    __syncthreads();
    float* gfc = gfr + (blockIdx.x & 3) * 512;
    {
        float v0 = sred[0][tid] + sred[1][tid] + sred[2][tid] + sred[3][tid];
        float v1 = sred[0][256 + tid] + sred[1][256 + tid] +
                   sred[2][256 + tid] + sred[3][256 + tid];
        atomicAdd(&gfc[tid], v0);
        atomicAdd(&gfc[256 + tid], v1);
    }
    __syncthreads();
    if (tid == 0)
        sticket = __hip_atomic_fetch_add(cntt, 1, __ATOMIC_ACQ_REL,
                                         __HIP_MEMORY_SCOPE_AGENT);
    __syncthreads();
    if (sticket != GF_GRID - 1) return;

    // ---- last block: finalize ----
    float a0 = __hip_atomic_load(&napart[tid * 4 + 0], __ATOMIC_RELAXED,
                                 __HIP_MEMORY_SCOPE_AGENT);
    float a1 = __hip_atomic_load(&napart[tid * 4 + 1], __ATOMIC_RELAXED,
                                 __HIP_MEMORY_SCOPE_AGENT);
    float a2 = __hip_atomic_load(&napart[tid * 4 + 2], __ATOMIC_RELAXED,
                                 __HIP_MEMORY_SCOPE_AGENT);
    float a3 = __hip_atomic_load(&napart[tid * 4 + 3], __ATOMIC_RELAXED,
                                 __HIP_MEMORY_SCOPE_AGENT);
    #pragma unroll
    for (int off = 32; off; off >>= 1) {
        a0 += __shfl_down(a0, off);
        a1 += __shfl_down(a1, off);
        a2 += __shfl_down(a2, off);
        a3 += __shfl_down(a3, off);
    }
    if (lane == 0) {
        red[wave][0] = a0; red[wave][1] = a1;
        red[wave][2] = a2; red[wave][3] = a3;
    }
    __syncthreads();
    if (tid < 4)
        fin[tid] = red[0][tid] + red[1][tid] + red[2][tid] + red[3][tid];
    __syncthreads();
    float P0 = fin[3];
    float P1 = (float)N_NODES - P0;
    {
        float g0 = 0.f, g1 = 0.f;
        #pragma unroll
        for (int k = 0; k < 4; ++k) {
            g0 += __hip_atomic_load(&gfr[k * 512 + tid], __ATOMIC_RELAXED,
                                    __HIP_MEMORY_SCOPE_AGENT);
            g1 += __hip_atomic_load(&gfr[k * 512 + 256 + tid], __ATOMIC_RELAXED,
                                    __HIP_MEMORY_SCOPE_AGENT);
        }
        float bv = b2[tid];
        g0 += P0 * bv;
        g1 += P1 * bv;
        out[tid] = 0.5f * (g0 + g1);
        out[256 + tid] = fminf(fmaxf(g0, -100.f), 100.f);
        out[512 + tid] = fminf(fmaxf(g1, -100.f), 100.f);
    }
    if (tid == 0) {
        float Ssd = fin[0], Ss = fin[1], Sd = fin[2];
        float n00 = Ssd;
        float n01 = Ss - Ssd;
        float n10 = Sd - Ssd;
        float n11 = (float)N_EDGES - Ss - Sd + Ssd;
        float den0 = fmaxf(fabsf(n00) + fabsf(n01), 1e-12f);
        float den1 = fmaxf(fabsf(n10) + fabsf(n11), 1e-12f);
        float x0 = n00 / den0 - 1.0f;
        float x1 = n11 / den1 - 1.0f;
        out[768] = 0.5f * (x0 * x0 + x1 * x1);
    }
}

// ---------------- launch ----------------

extern "C" void kernel_launch(void* const* d_in, const int* in_sizes, int n_in,
                              void* d_out, int out_size, void* d_ws, size_t ws_size,
                              hipStream_t stream) {
    const float* features = (const float*)d_in[0];
    const int* edges = (const int*)d_in[1];
    const int* src = edges;
    const int* dst = edges + N_EDGES;
    const float* W1 = (const float*)d_in[2];
    const float* b1 = (const float*)d_in[3];
    const float* W2 = (const float*)d_in[4];
    const float* b2 = (const float*)d_in[5];
    const float* fc1_w = (const float*)d_in[6];
    const float* fc1_b = (const float*)d_in[7];
    const float* fc2_w = (const float*)d_in[8];
    const float* fc2_b = (const float*)d_in[9];
    float* out = (float*)d_out;

    char* ws = (char*)d_ws;
    auto carve = [&](size_t bytes) {
        void* q = (void*)ws;
        ws += (bytes + 255) & ~(size_t)255;
        return q;
    };
    // contiguous memset region: cur + cur2 + gfr + ticket
    int* cur = (int*)carve(N_NODES * 4);             // 65536
    int* cur2 = (int*)carve(N_NODES * 4);            // 65536
    float* gfr = (float*)carve(4 * 512 * 4);         // 8192
    int* cnt_na = (int*)carve(256);                  // 256
    const size_t MEMSET_BYTES = 65536 + 65536 + 8192 + 256;

    ushort_t* col = (ushort_t*)carve((size_t)N_NODES * DEG_CAP * 2);   // 3.1 MB
    ushort_t* col2 = (ushort_t*)carve((size_t)N_NODES * DEG_CAP * 2);  // 3.1 MB
    float* packf = (float*)carve((size_t)(N_NODES + 1) * 4 * 4);
    float* napart = (float*)carve(GF_GRID * 4 * 4);
    ushort_t* fc1bf = (ushort_t*)carve(64 * 256 * 2);
    float* c1f = (float*)carve(64 * 4);
    uchar_t* zs8 = (uchar_t*)carve((size_t)(N_NODES + 1) * F_IN);      // 2.1 MB
    ushort_t* W1t = (ushort_t*)carve(256 * 128 * 2);
    ushort_t* W2t = (ushort_t*)carve(256 * 256 * 2);
    uchar_t* bufY8 = (uchar_t*)carve((size_t)(N_NODES + 1) * 256);     // 4.2 MB
    uchar_t* ts8 = (uchar_t*)carve((size_t)(N_NODES + 1) * 64);        // 1.05 MB

    hipMemsetAsync(cur, 0, MEMSET_BYTES, stream);

    prep_fill<<<4544, 256, 0, stream>>>(src, dst, W1, W2, fc1_w,
                                        cur, cur2, col, col2, W1t, W2t, fc1bf);
    scale_feat<<<2049, 256, 0, stream>>>(features, cur, cur2, zs8, ts8,
                                         col, col2, fc1_w, b2, fc1_b, c1f,
                                         packf);
    fused_layer1<<<N_NODES / 16, 512, 0, stream>>>(
        zs8, cur, col, b1, W1t, W2t, fc1bf, bufY8, ts8);
    assign2<<<N_NODES / 16, 512, 0, stream>>>(
        ts8, cur, col, c1f, fc2_w, fc2_b, packf);
    gf_fin<<<GF_GRID, 256, 0, stream>>>(bufY8, packf, cur, cur2, col, col2,
                                        napart, gfr, b2, cnt_na, out);
}

// Round 11
// 206.906 us; speedup vs baseline: 6.4083x; 1.0111x over previous
//
#include <hip/hip_runtime.h>
#include <hip/hip_bf16.h>
#include <hip/hip_fp8.h>
#include <math.h>

#define N_NODES 16384
#define N_EDGES 524288
#define F_IN 128
#define H1 256
#define H2 256
#define D1 64
#define NA_GRID 512
#define DEG_CAP 96        // Poisson(32): max deg over 16384 nodes ~57; P(>96)~1e-20
#define SENT 16384        // sentinel index -> zeroed row

typedef __attribute__((ext_vector_type(8))) short short8;
typedef __attribute__((ext_vector_type(4))) float floatx4;
typedef unsigned short ushort_t;
typedef unsigned int uint_t;
typedef unsigned char uchar_t;

__device__ inline float bf2f(ushort_t u) {
    union { uint_t i; float f; } v;
    v.i = ((uint_t)u) << 16;
    return v.f;
}
__device__ inline ushort_t f2bs(float x) {
    __hip_bfloat16 h = __float2bfloat16(x);   // RNE
    return *reinterpret_cast<ushort_t*>(&h);
}
__device__ inline uint_t pack2(float lo, float hi) {
    return (uint_t)f2bs(lo) | ((uint_t)f2bs(hi) << 16);
}
// ---- OCP fp8 e4m3 (gfx950 HW cvt) ----
__device__ inline float f8tof(uint_t b) {
    __hip_fp8_e4m3 h; h.__x = (__hip_fp8_storage_t)(b & 0xff);
    return (float)h;
}
__device__ inline uint_t ftof8(float v) {
    __hip_fp8_e4m3 h(v);                      // RNE, satfinite
    return (uint_t)h.__x;
}

// ------- bucket fill (histogram) + weight converts, one dispatch -------
// Scatter is phased over 8 dst-range partitions: live bucket region per pass
// ~400 KB -> L2-resident per XCD -> each bucket line written back ~once
// (vs ~8x write amplification when the whole 3.1 MB array thrashes).
__global__ __launch_bounds__(256) void prep_fill(
    const int* __restrict__ src, const int* __restrict__ dst,
    const float* __restrict__ W1, const float* __restrict__ W2,
    const float* __restrict__ fc1_w,
    int* __restrict__ cur, ushort_t* __restrict__ col,
    ushort_t* __restrict__ W1t, ushort_t* __restrict__ W2t,
    ushort_t* __restrict__ fc1bf) {
    int b = blockIdx.x, t = threadIdx.x;
    if (b < 2048) {
        int e = b * 256 + t;
        int s = src[e];
        int d = dst[e];
        int part = d >> 11;                  // 8 partitions of 2048 dst each
        #pragma unroll
        for (int p = 0; p < 8; ++p) {
            if (part == p) {
                int pos = atomicAdd(&cur[d], 1);
                if (pos < DEG_CAP) col[d * DEG_CAP + pos] = (ushort_t)s;
            }
        }
    } else if (b < 2176) {
        int idx = (b - 2048) * 256 + t;
        int n = idx >> 7, k = idx & 127;
        W1t[idx] = f2bs(W1[k * 256 + n]);
    } else if (b < 2432) {
        int idx = (b - 2176) * 256 + t;
        int n = idx >> 8, k = idx & 255;
        W2t[idx] = f2bs(W2[k * 256 + n]);
    } else {
        int idx = (b - 2432) * 256 + t;
        fc1bf[idx] = f2bs(fc1_w[idx]);
    }
}

// ------- zs8 = fp8(dinv*feat); pad col buckets to x16 with SENT; sentinels
__global__ __launch_bounds__(256) void scale_feat(
    const float* __restrict__ features, const int* __restrict__ cnt,
    uchar_t* __restrict__ zs8, uchar_t* __restrict__ bufY8,
    ushort_t* __restrict__ col) {
    int b = blockIdx.x, t = threadIdx.x;
    if (b == 2048) {
        uint4 z4 = {0u, 0u, 0u, 0u};
        if (t < 8)
            *(uint4*)&zs8[(size_t)SENT * 128 + t * 16] = z4;
        else if (t >= 64 && t < 80)
            *(uint4*)&bufY8[(size_t)SENT * 256 + (t - 64) * 16] = z4;
        return;
    }
    int gid = b * 256 + t;
    int node = gid >> 5;
    int hl = gid & 31;
    int deg = cnt[node];
    float d = rsqrtf((float)(deg + 1));
    float4 v = *(const float4*)&features[gid * 4];
    uint_t p = ftof8(v.x * d) | (ftof8(v.y * d) << 8) |
               (ftof8(v.z * d) << 16) | (ftof8(v.w * d) << 24);
    *(uint_t*)&zs8[gid * 4] = p;
    if (deg < DEG_CAP) {
        int pad = (16 - (deg & 15)) & 15;
        if (hl < pad) col[node * DEG_CAP + deg + hl] = (ushort_t)SENT;
    }
}

// ===== fused agg1 -> gemm1 -> gemm2, 16 nodes/block, 8 waves (512 thr) =====
__global__ __launch_bounds__(512, 4) void fused_layer1(
    const uchar_t* __restrict__ zs8, const int* __restrict__ cnt,
    const ushort_t* __restrict__ col, const float* __restrict__ b1,
    const ushort_t* __restrict__ W1t, const ushort_t* __restrict__ W2t,
    uchar_t* __restrict__ bufY8) {
    __shared__ __align__(16) ushort_t Az[16 * 136];
    __shared__ __align__(16) ushort_t Ah[16 * 264];
    __shared__ __align__(8) uint_t scol[768];
    const int tid = threadIdx.x;
    const int lane = tid & 63;
    const int wave = tid >> 6;
    const int m = lane & 15;
    const int quad = lane >> 4;
    const int row0 = blockIdx.x * 16;
    const uint_t* colu = (const uint_t*)col;

    if (tid < 384)
        *(uint2*)&scol[tid * 2] = *(const uint2*)&colu[row0 * 48 + tid * 2];
    __syncthreads();
    {
        const int nl0 = wave * 2, nl1 = wave * 2 + 1;
        const int node0 = row0 + nl0, node1 = row0 + nl1;
        const int foff = lane * 2;
        const int deg0 = cnt[node0], deg1 = cnt[node1];
        const int nb0 = (min(deg0, DEG_CAP) + 15) >> 4;
        const int nb1 = (min(deg1, DEG_CAP) + 15) >> 4;
        const int nbm = max(nb0, nb1);
        ushort_t s0 = *(const ushort_t*)&zs8[(size_t)node0 * 128 + foff];
        ushort_t s1 = *(const ushort_t*)&zs8[(size_t)node1 * 128 + foff];
        float a00 = f8tof(s0), a01 = f8tof(s0 >> 8);
        float a10 = f8tof(s1), a11 = f8tof(s1 >> 8);
        for (int tb = 0; tb < nbm; ++tb) {
            const bool p0 = tb < nb0, p1 = tb < nb1;
            uint_t w0[8], w1[8];
            if (p0) {
                #pragma unroll
                for (int k = 0; k < 8; ++k) w0[k] = scol[nl0 * 48 + tb * 8 + k];
            }
            if (p1) {
                #pragma unroll
                for (int k = 0; k < 8; ++k) w1[k] = scol[nl1 * 48 + tb * 8 + k];
            }
            ushort_t g0[16], g1[16];
            if (p0) {
                #pragma unroll
                for (int k = 0; k < 8; ++k) {
                    int j0 = w0[k] & 0xffff, j1 = w0[k] >> 16;
                    g0[2 * k]     = *(const ushort_t*)&zs8[(size_t)j0 * 128 + foff];
                    g0[2 * k + 1] = *(const ushort_t*)&zs8[(size_t)j1 * 128 + foff];
                }
            }
            if (p1) {
                #pragma unroll
                for (int k = 0; k < 8; ++k) {
                    int j0 = w1[k] & 0xffff, j1 = w1[k] >> 16;
                    g1[2 * k]     = *(const ushort_t*)&zs8[(size_t)j0 * 128 + foff];
                    g1[2 * k + 1] = *(const ushort_t*)&zs8[(size_t)j1 * 128 + foff];
                }
            }
            if (p0) {
                #pragma unroll
                for (int q = 0; q < 16; ++q) {
                    a00 += f8tof(g0[q]); a01 += f8tof(g0[q] >> 8);
                }
            }
            if (p1) {
                #pragma unroll
                for (int q = 0; q < 16; ++q) {
                    a10 += f8tof(g1[q]); a11 += f8tof(g1[q] >> 8);
                }
            }
        }
        float dn0 = rsqrtf((float)(deg0 + 1));
        float dn1 = rsqrtf((float)(deg1 + 1));
        *(uint_t*)&Az[nl0 * 136 + foff] = pack2(a00 * dn0, a01 * dn0);
        *(uint_t*)&Az[nl1 * 136 + foff] = pack2(a10 * dn1, a11 * dn1);
    }
    __syncthreads();
    const int wcol0 = wave * 32;
    floatx4 acc[2];
    const floatx4 zero4 = {0.f, 0.f, 0.f, 0.f};
    acc[0] = zero4; acc[1] = zero4;
    #pragma unroll
    for (int k0 = 0; k0 < 128; k0 += 32) {
        short8 a = *(const short8*)&Az[m * 136 + k0 + quad * 8];
        #pragma unroll
        for (int j = 0; j < 2; ++j) {
            short8 bb = *(const short8*)
                &W1t[(size_t)(wcol0 + j * 16 + m) * 128 + k0 + quad * 8];
            acc[j] = __builtin_amdgcn_mfma_f32_16x16x32_bf16(a, bb, acc[j], 0, 0, 0);
        }
    }
    #pragma unroll
    for (int j = 0; j < 2; ++j) {
        int cg_ = wcol0 + j * 16 + m;
        float bv = b1[cg_];
        #pragma unroll
        for (int r = 0; r < 4; ++r) {
            float v = fmaxf(acc[j][r] + bv, 0.0f);
            Ah[(quad * 4 + r) * 264 + cg_] = f2bs(v);
        }
    }
    __syncthreads();
    acc[0] = zero4; acc[1] = zero4;
    #pragma unroll
    for (int k0 = 0; k0 < 256; k0 += 32) {
        short8 a = *(const short8*)&Ah[m * 264 + k0 + quad * 8];
        #pragma unroll
        for (int j = 0; j < 2; ++j) {
            short8 bb = *(const short8*)
                &W2t[(size_t)(wcol0 + j * 16 + m) * 256 + k0 + quad * 8];
            acc[j] = __builtin_amdgcn_mfma_f32_16x16x32_bf16(a, bb, acc[j], 0, 0, 0);
        }
    }
    float rs4[4];
    #pragma unroll
    for (int r = 0; r < 4; ++r)
        rs4[r] = rsqrtf((float)(cnt[row0 + quad * 4 + r] + 1));
    #pragma unroll
    for (int j = 0; j < 2; ++j) {
        int cg_ = wcol0 + j * 16 + m;
        #pragma unroll
        for (int r = 0; r < 4; ++r)
            bufY8[(size_t)(row0 + quad * 4 + r) * 256 + cg_] =
                (uchar_t)ftof8(acc[j][r] * rs4[r]);
    }
}

// ===== fused agg2 -> fc1 -> tanh -> fc2 -> softmax -> gf pool (8 waves) =====
__global__ __launch_bounds__(512, 4) void fused_assign(
    const uchar_t* __restrict__ bufY8, const int* __restrict__ cnt,
    const ushort_t* __restrict__ col, const float* __restrict__ b2,
    const ushort_t* __restrict__ fc1bf, const float* __restrict__ fc1_b,
    const float* __restrict__ fc2_w, const float* __restrict__ fc2_b,
    float* __restrict__ assignp, float* __restrict__ gfr) {
    __shared__ __align__(16) ushort_t Ah[16 * 264];
    __shared__ __align__(8) uint_t scol[768];
    __shared__ float sha[16][65];
    __shared__ float sas0[16], sas1[16];
    const int tid = threadIdx.x;
    const int lane = tid & 63;
    const int wave = tid >> 6;
    const int m = lane & 15;
    const int quad = lane >> 4;
    const int row0 = blockIdx.x * 16;
    const uint_t* colu = (const uint_t*)col;

    if (tid < 384)
        *(uint2*)&scol[tid * 2] = *(const uint2*)&colu[row0 * 48 + tid * 2];
    __syncthreads();
    {
        const int nl0 = wave * 2, nl1 = wave * 2 + 1;
        const int node0 = row0 + nl0, node1 = row0 + nl1;
        const int foff = lane * 4;
        const int deg0 = cnt[node0], deg1 = cnt[node1];
        const int nb0 = (min(deg0, DEG_CAP) + 15) >> 4;
        const int nb1 = (min(deg1, DEG_CAP) + 15) >> 4;
        const int nbm = max(nb0, nb1);
        uint_t sv0 = *(const uint_t*)&bufY8[(size_t)node0 * 256 + foff];
        uint_t sv1 = *(const uint_t*)&bufY8[(size_t)node1 * 256 + foff];
        float a00 = f8tof(sv0),       a01 = f8tof(sv0 >> 8);
        float a02 = f8tof(sv0 >> 16), a03 = f8tof(sv0 >> 24);
        float a10 = f8tof(sv1),       a11 = f8tof(sv1 >> 8);
        float a12 = f8tof(sv1 >> 16), a13 = f8tof(sv1 >> 24);
        for (int tb = 0; tb < nbm; ++tb) {
            const bool p0 = tb < nb0, p1 = tb < nb1;
            uint_t w0[8], w1[8];
            if (p0) {
                #pragma unroll
                for (int k = 0; k < 8; ++k) w0[k] = scol[nl0 * 48 + tb * 8 + k];
            }
            if (p1) {
                #pragma unroll
                for (int k = 0; k < 8; ++k) w1[k] = scol[nl1 * 48 + tb * 8 + k];
            }
            uint_t g0[16], g1[16];
            if (p0) {
                #pragma unroll
                for (int k = 0; k < 8; ++k) {
                    int j0 = w0[k] & 0xffff, j1 = w0[k] >> 16;
                    g0[2 * k]     = *(const uint_t*)&bufY8[(size_t)j0 * 256 + foff];
                    g0[2 * k + 1] = *(const uint_t*)&bufY8[(size_t)j1 * 256 + foff];
                }
            }
            if (p1) {
                #pragma unroll
                for (int k = 0; k < 8; ++k) {
                    int j0 = w1[k] & 0xffff, j1 = w1[k] >> 16;
                    g1[2 * k]     = *(const uint_t*)&bufY8[(size_t)j0 * 256 + foff];
                    g1[2 * k + 1] = *(const uint_t*)&bufY8[(size_t)j1 * 256 + foff];
                }
            }
            if (p0) {
                #pragma unroll
                for (int q = 0; q < 16; ++q) {
                    a00 += f8tof(g0[q]);       a01 += f8tof(g0[q] >> 8);
                    a02 += f8tof(g0[q] >> 16); a03 += f8tof(g0[q] >> 24);
                }
            }
            if (p1) {
                #pragma unroll
                for (int q = 0; q < 16; ++q) {
                    a10 += f8tof(g1[q]);       a11 += f8tof(g1[q] >> 8);
                    a12 += f8tof(g1[q] >> 16); a13 += f8tof(g1[q] >> 24);
                }
            }
        }
        float di0 = rsqrtf((float)(deg0 + 1));
        float di1 = rsqrtf((float)(deg1 + 1));
        float4 bv = *(const float4*)&b2[foff];
        uint2 pk;
        pk.x = pack2(a00 * di0 + bv.x, a01 * di0 + bv.y);
        pk.y = pack2(a02 * di0 + bv.z, a03 * di0 + bv.w);
        *(uint2*)&Ah[nl0 * 264 + foff] = pk;
        pk.x = pack2(a10 * di1 + bv.x, a11 * di1 + bv.y);
        pk.y = pack2(a12 * di1 + bv.z, a13 * di1 + bv.w);
        *(uint2*)&Ah[nl1 * 264 + foff] = pk;
    }
    __syncthreads();
    if (wave < 4) {
        floatx4 acc = {0.f, 0.f, 0.f, 0.f};
        #pragma unroll
        for (int k0 = 0; k0 < 256; k0 += 32) {
            short8 a = *(const short8*)&Ah[m * 264 + k0 + quad * 8];
            short8 bb = *(const short8*)
                &fc1bf[(size_t)(wave * 16 + m) * 256 + k0 + quad * 8];
            acc = __builtin_amdgcn_mfma_f32_16x16x32_bf16(a, bb, acc, 0, 0, 0);
        }
        int cg_ = wave * 16 + m;
        float bv = fc1_b[cg_];
        #pragma unroll
        for (int r = 0; r < 4; ++r)
            sha[quad * 4 + r][cg_] = tanhf(acc[r] + bv);
    }
    __syncthreads();
    if (tid < 16) {
        float p0 = fc2_b[0], p1 = fc2_b[1];
        #pragma unroll 8
        for (int t = 0; t < 64; ++t) {
            float a = sha[tid][t];
            p0 += a * fc2_w[t];
            p1 += a * fc2_w[64 + t];
        }
        float mx = fmaxf(p0, p1);
        float e0 = expf(p0 - mx), e1 = expf(p1 - mx);
        float inv = 1.0f / (e0 + e1);
        assignp[row0 + tid] = e0 * inv;
        sas0[tid] = e0 * inv; sas1[tid] = e1 * inv;
    }
    __syncthreads();
    {
        const int f = tid & 255;
        const int which = tid >> 8;
        const float* sv = which ? sas1 : sas0;
        float acc = 0.f;
        #pragma unroll
        for (int i = 0; i < 16; ++i)
            acc += sv[i] * bf2f(Ah[i * 264 + f]);
        float* gfc = gfr + (blockIdx.x & 3) * 512;
        atomicAdd(&gfc[which * 256 + f], acc);
    }
}

// ===== newadj + last-block finalize (512-block ticket) =====
__global__ __launch_bounds__(256) void newadj_fin(
    const int* __restrict__ src, const int* __restrict__ dst,
    const float* __restrict__ assignp, float* __restrict__ napart,
    int* __restrict__ cntt, const float* __restrict__ gfr,
    float* __restrict__ out) {
    __shared__ float red[4][3];
    __shared__ int sticket;
    const int tid = threadIdx.x;
    const int b = blockIdx.x;
    const int lane = tid & 63;
    const int wave = tid >> 6;

    float ss = 0.f, sd = 0.f, ssd = 0.f;
    {
        int g = (b * 256 + tid) * 4;
        int4 sv = *(const int4*)&src[g];
        int4 dv = *(const int4*)&dst[g];
        float s0 = assignp[sv.x], s1 = assignp[sv.y];
        float s2 = assignp[sv.z], s3 = assignp[sv.w];
        float d0 = assignp[dv.x], d1 = assignp[dv.y];
        float d2 = assignp[dv.z], d3 = assignp[dv.w];
        ss = s0 + s1 + s2 + s3;
        sd = d0 + d1 + d2 + d3;
        ssd = s0 * d0 + s1 * d1 + s2 * d2 + s3 * d3;
    }
    #pragma unroll
    for (int off = 32; off; off >>= 1) {
        ss += __shfl_down(ss, off);
        sd += __shfl_down(sd, off);
        ssd += __shfl_down(ssd, off);
    }
    if (lane == 0) {
        red[wave][0] = ssd; red[wave][1] = ss; red[wave][2] = sd;
    }
    __syncthreads();
    if (tid < 3) {
        float v = red[0][tid] + red[1][tid] + red[2][tid] + red[3][tid];
        __hip_atomic_store(&napart[b * 4 + tid], v, __ATOMIC_RELEASE,
                           __HIP_MEMORY_SCOPE_AGENT);
    }
    __syncthreads();
    if (tid == 0)
        sticket = __hip_atomic_fetch_add(cntt, 1, __ATOMIC_ACQ_REL,
                                         __HIP_MEMORY_SCOPE_AGENT);
    __syncthreads();
    if (sticket != NA_GRID - 1) return;

    float acc = 0.f;
    if (wave < 3) {
        for (int i = lane; i < NA_GRID; i += 64)
            acc += __hip_atomic_load(&napart[i * 4 + wave], __ATOMIC_RELAXED,
                                     __HIP_MEMORY_SCOPE_AGENT);
    }
    #pragma unroll
    for (int off = 32; off; off >>= 1) acc += __shfl_down(acc, off);
    __shared__ float na[3];
    if (lane == 0 && wave < 3) na[wave] = acc;
    __syncthreads();
    float g0 = gfr[tid] + gfr[512 + tid] + gfr[1024 + tid] + gfr[1536 + tid];
    float g1 = gfr[256 + tid] + gfr[768 + tid] + gfr[1280 + tid] + gfr[1792 + tid];
    out[tid] = 0.5f * (g0 + g1);
    out[256 + tid] = fminf(fmaxf(g0, -100.f), 100.f);
    out[512 + tid] = fminf(fmaxf(g1, -100.f), 100.f);
    if (tid == 0) {
        float Ssd = na[0], Ss = na[1], Sd = na[2];
        float n00 = Ssd;
        float n01 = Ss - Ssd;
        float n10 = Sd - Ssd;
        float n11 = (float)N_EDGES - Ss - Sd + Ssd;
        float den0 = fmaxf(fabsf(n00) + fabsf(n01), 1e-12f);
        float den1 = fmaxf(fabsf(n10) + fabsf(n11), 1e-12f);
        float x0 = n00 / den0 - 1.0f;
        float x1 = n11 / den1 - 1.0f;
        out[768] = 0.5f * (x0 * x0 + x1 * x1);
    }
}

// ---------------- launch ----------------

extern "C" void kernel_launch(void* const* d_in, const int* in_sizes, int n_in,
                              void* d_out, int out_size, void* d_ws, size_t ws_size,
                              hipStream_t stream) {
    const float* features = (const float*)d_in[0];
    const int* edges = (const int*)d_in[1];
    const int* src = edges;
    const int* dst = edges + N_EDGES;
    const float* W1 = (const float*)d_in[2];
    const float* b1 = (const float*)d_in[3];
    const float* W2 = (const float*)d_in[4];
    const float* b2 = (const float*)d_in[5];
    const float* fc1_w = (const float*)d_in[6];
    const float* fc1_b = (const float*)d_in[7];
    const float* fc2_w = (const float*)d_in[8];
    const float* fc2_b = (const float*)d_in[9];
    float* out = (float*)d_out;

    char* ws = (char*)d_ws;
    auto carve = [&](size_t bytes) {
        void* q = (void*)ws;
        ws += (bytes + 255) & ~(size_t)255;
        return q;
    };
    // contiguous memset region: cur + gfr + cnt_na
    int* cur = (int*)carve(N_NODES * 4);             // 65536 B
    float* gfr = (float*)carve(4 * 512 * 4);         // 8192 B
    int* cnt_na = (int*)carve(256);                  // 256 B
    ushort_t* col = (ushort_t*)carve((size_t)N_NODES * DEG_CAP * 2);  // 3.1 MB
    float* assignp = (float*)carve(N_NODES * 4);
    float* napart = (float*)carve(NA_GRID * 4 * 4);
    ushort_t* fc1bf = (ushort_t*)carve(64 * 256 * 2);
    uchar_t* zs8 = (uchar_t*)carve((size_t)(N_NODES + 1) * F_IN);     // 2.1 MB
    ushort_t* W1t = (ushort_t*)carve(256 * 128 * 2);
    ushort_t* W2t = (ushort_t*)carve(256 * 256 * 2);
    uchar_t* bufY8 = (uchar_t*)carve((size_t)(N_NODES + 1) * 256);    // 4.2 MB

    hipMemsetAsync(cur, 0, N_NODES * 4 + 4 * 512 * 4 + 256, stream);

    prep_fill<<<2496, 256, 0, stream>>>(src, dst, W1, W2, fc1_w,
                                        cur, col, W1t, W2t, fc1bf);
    scale_feat<<<2049, 256, 0, stream>>>(features, cur, zs8, bufY8, col);
    fused_layer1<<<N_NODES / 16, 512, 0, stream>>>(
        zs8, cur, col, b1, W1t, W2t, bufY8);
    fused_assign<<<N_NODES / 16, 512, 0, stream>>>(
        bufY8, cur, col, b2, fc1bf, fc1_b, fc2_w, fc2_b, assignp, gfr);
    newadj_fin<<<NA_GRID, 256, 0, stream>>>(src, dst, assignp, napart,
                                            cnt_na, gfr, out);
}

// Round 12
// 189.994 us; speedup vs baseline: 6.9787x; 1.0890x over previous
//
#include <hip/hip_runtime.h>
#include <hip/hip_bf16.h>
#include <hip/hip_fp8.h>
#include <math.h>

#define N_NODES 16384
#define N_EDGES 524288
#define F_IN 128
#define H1 256
#define H2 256
#define D1 64
#define NA_GRID 512
#define DEG_CAP 96        // Poisson(32): max deg over 16384 nodes ~57; P(>96)~1e-20
#define SENT 16384        // sentinel index -> zeroed row

typedef __attribute__((ext_vector_type(8))) short short8;
typedef __attribute__((ext_vector_type(4))) float floatx4;
typedef unsigned short ushort_t;
typedef unsigned int uint_t;
typedef unsigned char uchar_t;

__device__ inline float bf2f(ushort_t u) {
    union { uint_t i; float f; } v;
    v.i = ((uint_t)u) << 16;
    return v.f;
}
__device__ inline ushort_t f2bs(float x) {
    __hip_bfloat16 h = __float2bfloat16(x);   // RNE
    return *reinterpret_cast<ushort_t*>(&h);
}
__device__ inline uint_t pack2(float lo, float hi) {
    return (uint_t)f2bs(lo) | ((uint_t)f2bs(hi) << 16);
}
// ---- OCP fp8 e4m3 (gfx950 HW cvt) ----
__device__ inline float f8tof(uint_t b) {
    __hip_fp8_e4m3 h; h.__x = (__hip_fp8_storage_t)(b & 0xff);
    return (float)h;
}
__device__ inline uint_t ftof8(float v) {
    __hip_fp8_e4m3 h(v);                      // RNE, satfinite
    return (uint_t)h.__x;
}

// ------- bucket fill (histogram) + weight converts, one dispatch -------
// XCD-local scatter: block b reads edge slice b>>3, scatters ONLY edges with
// dst>>11 == b&7. With blockIdx%8 -> XCD round-robin, partition p's 392 KB
// (col+cur range) is written by XCD p alone -> lines stay in ONE L2, written
// back once (vs bouncing across 8 non-coherent L2s = 24 MB amplification).
// Each edge scattered exactly once regardless of the actual XCD mapping.
__global__ __launch_bounds__(256) void prep_fill(
    const int* __restrict__ src, const int* __restrict__ dst,
    const float* __restrict__ W1, const float* __restrict__ W2,
    const float* __restrict__ fc1_w,
    int* __restrict__ cur, ushort_t* __restrict__ col,
    ushort_t* __restrict__ W1t, ushort_t* __restrict__ W2t,
    ushort_t* __restrict__ fc1bf) {
    int b = blockIdx.x, t = threadIdx.x;
    if (b < 2048) {
        const int part = b & 7;              // dst partition (2048 nodes)
        const int e0 = (b >> 3) * 2048;      // edge slice (2048 edges)
        #pragma unroll
        for (int k = 0; k < 8; ++k) {
            int e = e0 + k * 256 + t;
            int d = dst[e];
            if ((d >> 11) == part) {
                int pos = atomicAdd(&cur[d], 1);
                if (pos < DEG_CAP) col[d * DEG_CAP + pos] = (ushort_t)src[e];
            }
        }
    } else if (b < 2176) {
        int idx = (b - 2048) * 256 + t;
        int n = idx >> 7, k = idx & 127;
        W1t[idx] = f2bs(W1[k * 256 + n]);
    } else if (b < 2432) {
        int idx = (b - 2176) * 256 + t;
        int n = idx >> 8, k = idx & 255;
        W2t[idx] = f2bs(W2[k * 256 + n]);
    } else {
        int idx = (b - 2432) * 256 + t;
        fc1bf[idx] = f2bs(fc1_w[idx]);
    }
}

// ------- zs8 = fp8(dinv*feat); pad col buckets to x16 with SENT; sentinels
__global__ __launch_bounds__(256) void scale_feat(
    const float* __restrict__ features, const int* __restrict__ cnt,
    uchar_t* __restrict__ zs8, uchar_t* __restrict__ bufY8,
    ushort_t* __restrict__ col) {
    int b = blockIdx.x, t = threadIdx.x;
    if (b == 2048) {
        uint4 z4 = {0u, 0u, 0u, 0u};
        if (t < 8)
            *(uint4*)&zs8[(size_t)SENT * 128 + t * 16] = z4;
        else if (t >= 64 && t < 80)
            *(uint4*)&bufY8[(size_t)SENT * 256 + (t - 64) * 16] = z4;
        return;
    }
    int gid = b * 256 + t;
    int node = gid >> 5;
    int hl = gid & 31;
    int deg = cnt[node];
    float d = rsqrtf((float)(deg + 1));
    float4 v = *(const float4*)&features[gid * 4];
    uint_t p = ftof8(v.x * d) | (ftof8(v.y * d) << 8) |
               (ftof8(v.z * d) << 16) | (ftof8(v.w * d) << 24);
    *(uint_t*)&zs8[gid * 4] = p;
    if (deg < DEG_CAP) {
        int pad = (16 - (deg & 15)) & 15;
        if (hl < pad) col[node * DEG_CAP + deg + hl] = (ushort_t)SENT;
    }
}

// ===== fused agg1 -> gemm1 -> gemm2, 16 nodes/block, 8 waves (512 thr) =====
__global__ __launch_bounds__(512, 4) void fused_layer1(
    const uchar_t* __restrict__ zs8, const int* __restrict__ cnt,
    const ushort_t* __restrict__ col, const float* __restrict__ b1,
    const ushort_t* __restrict__ W1t, const ushort_t* __restrict__ W2t,
    uchar_t* __restrict__ bufY8) {
    __shared__ __align__(16) ushort_t Az[16 * 136];
    __shared__ __align__(16) ushort_t Ah[16 * 264];
    __shared__ __align__(8) uint_t scol[768];
    const int tid = threadIdx.x;
    const int lane = tid & 63;
    const int wave = tid >> 6;
    const int m = lane & 15;
    const int quad = lane >> 4;
    const int row0 = blockIdx.x * 16;
    const uint_t* colu = (const uint_t*)col;

    if (tid < 384)
        *(uint2*)&scol[tid * 2] = *(const uint2*)&colu[row0 * 48 + tid * 2];
    __syncthreads();
    {
        const int nl0 = wave * 2, nl1 = wave * 2 + 1;
        const int node0 = row0 + nl0, node1 = row0 + nl1;
        const int foff = lane * 2;
        const int deg0 = cnt[node0], deg1 = cnt[node1];
        const int nb0 = (min(deg0, DEG_CAP) + 15) >> 4;
        const int nb1 = (min(deg1, DEG_CAP) + 15) >> 4;
        const int nbm = max(nb0, nb1);
        ushort_t s0 = *(const ushort_t*)&zs8[(size_t)node0 * 128 + foff];
        ushort_t s1 = *(const ushort_t*)&zs8[(size_t)node1 * 128 + foff];
        float a00 = f8tof(s0), a01 = f8tof(s0 >> 8);
        float a10 = f8tof(s1), a11 = f8tof(s1 >> 8);
        for (int tb = 0; tb < nbm; ++tb) {
            const bool p0 = tb < nb0, p1 = tb < nb1;
            uint_t w0[8], w1[8];
            if (p0) {
                #pragma unroll
                for (int k = 0; k < 8; ++k) w0[k] = scol[nl0 * 48 + tb * 8 + k];
            }
            if (p1) {
                #pragma unroll
                for (int k = 0; k < 8; ++k) w1[k] = scol[nl1 * 48 + tb * 8 + k];
            }
            ushort_t g0[16], g1[16];
            if (p0) {
                #pragma unroll
                for (int k = 0; k < 8; ++k) {
                    int j0 = w0[k] & 0xffff, j1 = w0[k] >> 16;
                    g0[2 * k]     = *(const ushort_t*)&zs8[(size_t)j0 * 128 + foff];
                    g0[2 * k + 1] = *(const ushort_t*)&zs8[(size_t)j1 * 128 + foff];
                }
            }
            if (p1) {
                #pragma unroll
                for (int k = 0; k < 8; ++k) {
                    int j0 = w1[k] & 0xffff, j1 = w1[k] >> 16;
                    g1[2 * k]     = *(const ushort_t*)&zs8[(size_t)j0 * 128 + foff];
                    g1[2 * k + 1] = *(const ushort_t*)&zs8[(size_t)j1 * 128 + foff];
                }
            }
            if (p0) {
                #pragma unroll
                for (int q = 0; q < 16; ++q) {
                    a00 += f8tof(g0[q]); a01 += f8tof(g0[q] >> 8);
                }
            }
            if (p1) {
                #pragma unroll
                for (int q = 0; q < 16; ++q) {
                    a10 += f8tof(g1[q]); a11 += f8tof(g1[q] >> 8);
                }
            }
        }
        float dn0 = rsqrtf((float)(deg0 + 1));
        float dn1 = rsqrtf((float)(deg1 + 1));
        *(uint_t*)&Az[nl0 * 136 + foff] = pack2(a00 * dn0, a01 * dn0);
        *(uint_t*)&Az[nl1 * 136 + foff] = pack2(a10 * dn1, a11 * dn1);
    }
    __syncthreads();
    const int wcol0 = wave * 32;
    floatx4 acc[2];
    const floatx4 zero4 = {0.f, 0.f, 0.f, 0.f};
    acc[0] = zero4; acc[1] = zero4;
    #pragma unroll
    for (int k0 = 0; k0 < 128; k0 += 32) {
        short8 a = *(const short8*)&Az[m * 136 + k0 + quad * 8];
        #pragma unroll
        for (int j = 0; j < 2; ++j) {
            short8 bb = *(const short8*)
                &W1t[(size_t)(wcol0 + j * 16 + m) * 128 + k0 + quad * 8];
            acc[j] = __builtin_amdgcn_mfma_f32_16x16x32_bf16(a, bb, acc[j], 0, 0, 0);
        }
    }
    #pragma unroll
    for (int j = 0; j < 2; ++j) {
        int cg_ = wcol0 + j * 16 + m;
        float bv = b1[cg_];
        #pragma unroll
        for (int r = 0; r < 4; ++r) {
            float v = fmaxf(acc[j][r] + bv, 0.0f);
            Ah[(quad * 4 + r) * 264 + cg_] = f2bs(v);
        }
    }
    __syncthreads();
    acc[0] = zero4; acc[1] = zero4;
    #pragma unroll
    for (int k0 = 0; k0 < 256; k0 += 32) {
        short8 a = *(const short8*)&Ah[m * 264 + k0 + quad * 8];
        #pragma unroll
        for (int j = 0; j < 2; ++j) {
            short8 bb = *(const short8*)
                &W2t[(size_t)(wcol0 + j * 16 + m) * 256 + k0 + quad * 8];
            acc[j] = __builtin_amdgcn_mfma_f32_16x16x32_bf16(a, bb, acc[j], 0, 0, 0);
        }
    }
    float rs4[4];
    #pragma unroll
    for (int r = 0; r < 4; ++r)
        rs4[r] = rsqrtf((float)(cnt[row0 + quad * 4 + r] + 1));
    #pragma unroll
    for (int j = 0; j < 2; ++j) {
        int cg_ = wcol0 + j * 16 + m;
        #pragma unroll
        for (int r = 0; r < 4; ++r)
            bufY8[(size_t)(row0 + quad * 4 + r) * 256 + cg_] =
                (uchar_t)ftof8(acc[j][r] * rs4[r]);
    }
}

// ===== fused agg2 -> fc1 -> tanh -> fc2 -> softmax -> gf pool (8 waves) =====
__global__ __launch_bounds__(512, 4) void fused_assign(
    const uchar_t* __restrict__ bufY8, const int* __restrict__ cnt,
    const ushort_t* __restrict__ col, const float* __restrict__ b2,
    const ushort_t* __restrict__ fc1bf, const float* __restrict__ fc1_b,
    const float* __restrict__ fc2_w, const float* __restrict__ fc2_b,
    float* __restrict__ assignp, float* __restrict__ gfr) {
    __shared__ __align__(16) ushort_t Ah[16 * 264];
    __shared__ __align__(8) uint_t scol[768];
    __shared__ float sha[16][65];
    __shared__ float sas0[16], sas1[16];
    const int tid = threadIdx.x;
    const int lane = tid & 63;
    const int wave = tid >> 6;
    const int m = lane & 15;
    const int quad = lane >> 4;
    const int row0 = blockIdx.x * 16;
    const uint_t* colu = (const uint_t*)col;

    if (tid < 384)
        *(uint2*)&scol[tid * 2] = *(const uint2*)&colu[row0 * 48 + tid * 2];
    __syncthreads();
    {
        const int nl0 = wave * 2, nl1 = wave * 2 + 1;
        const int node0 = row0 + nl0, node1 = row0 + nl1;
        const int foff = lane * 4;
        const int deg0 = cnt[node0], deg1 = cnt[node1];
        const int nb0 = (min(deg0, DEG_CAP) + 15) >> 4;
        const int nb1 = (min(deg1, DEG_CAP) + 15) >> 4;
        const int nbm = max(nb0, nb1);
        uint_t sv0 = *(const uint_t*)&bufY8[(size_t)node0 * 256 + foff];
        uint_t sv1 = *(const uint_t*)&bufY8[(size_t)node1 * 256 + foff];
        float a00 = f8tof(sv0),       a01 = f8tof(sv0 >> 8);
        float a02 = f8tof(sv0 >> 16), a03 = f8tof(sv0 >> 24);
        float a10 = f8tof(sv1),       a11 = f8tof(sv1 >> 8);
        float a12 = f8tof(sv1 >> 16), a13 = f8tof(sv1 >> 24);
        for (int tb = 0; tb < nbm; ++tb) {
            const bool p0 = tb < nb0, p1 = tb < nb1;
            uint_t w0[8], w1[8];
            if (p0) {
                #pragma unroll
                for (int k = 0; k < 8; ++k) w0[k] = scol[nl0 * 48 + tb * 8 + k];
            }
            if (p1) {
                #pragma unroll
                for (int k = 0; k < 8; ++k) w1[k] = scol[nl1 * 48 + tb * 8 + k];
            }
            uint_t g0[16], g1[16];
            if (p0) {
                #pragma unroll
                for (int k = 0; k < 8; ++k) {
                    int j0 = w0[k] & 0xffff, j1 = w0[k] >> 16;
                    g0[2 * k]     = *(const uint_t*)&bufY8[(size_t)j0 * 256 + foff];
                    g0[2 * k + 1] = *(const uint_t*)&bufY8[(size_t)j1 * 256 + foff];
                }
            }
            if (p1) {
                #pragma unroll
                for (int k = 0; k < 8; ++k) {
                    int j0 = w1[k] & 0xffff, j1 = w1[k] >> 16;
                    g1[2 * k]     = *(const uint_t*)&bufY8[(size_t)j0 * 256 + foff];
                    g1[2 * k + 1] = *(const uint_t*)&bufY8[(size_t)j1 * 256 + foff];
                }
            }
            if (p0) {
                #pragma unroll
                for (int q = 0; q < 16; ++q) {
                    a00 += f8tof(g0[q]);       a01 += f8tof(g0[q] >> 8);
                    a02 += f8tof(g0[q] >> 16); a03 += f8tof(g0[q] >> 24);
                }
            }
            if (p1) {
                #pragma unroll
                for (int q = 0; q < 16; ++q) {
                    a10 += f8tof(g1[q]);       a11 += f8tof(g1[q] >> 8);
                    a12 += f8tof(g1[q] >> 16); a13 += f8tof(g1[q] >> 24);
                }
            }
        }
        float di0 = rsqrtf((float)(deg0 + 1));
        float di1 = rsqrtf((float)(deg1 + 1));
        float4 bv = *(const float4*)&b2[foff];
        uint2 pk;
        pk.x = pack2(a00 * di0 + bv.x, a01 * di0 + bv.y);
        pk.y = pack2(a02 * di0 + bv.z, a03 * di0 + bv.w);
        *(uint2*)&Ah[nl0 * 264 + foff] = pk;
        pk.x = pack2(a10 * di1 + bv.x, a11 * di1 + bv.y);
        pk.y = pack2(a12 * di1 + bv.z, a13 * di1 + bv.w);
        *(uint2*)&Ah[nl1 * 264 + foff] = pk;
    }
    __syncthreads();
    if (wave < 4) {
        floatx4 acc = {0.f, 0.f, 0.f, 0.f};
        #pragma unroll
        for (int k0 = 0; k0 < 256; k0 += 32) {
            short8 a = *(const short8*)&Ah[m * 264 + k0 + quad * 8];
            short8 bb = *(const short8*)
                &fc1bf[(size_t)(wave * 16 + m) * 256 + k0 + quad * 8];
            acc = __builtin_amdgcn_mfma_f32_16x16x32_bf16(a, bb, acc, 0, 0, 0);
        }
        int cg_ = wave * 16 + m;
        float bv = fc1_b[cg_];
        #pragma unroll
        for (int r = 0; r < 4; ++r)
            sha[quad * 4 + r][cg_] = tanhf(acc[r] + bv);
    }
    __syncthreads();
    if (tid < 16) {
        float p0 = fc2_b[0], p1 = fc2_b[1];
        #pragma unroll 8
        for (int t = 0; t < 64; ++t) {
            float a = sha[tid][t];
            p0 += a * fc2_w[t];
            p1 += a * fc2_w[64 + t];
        }
        float mx = fmaxf(p0, p1);
        float e0 = expf(p0 - mx), e1 = expf(p1 - mx);
        float inv = 1.0f / (e0 + e1);
        assignp[row0 + tid] = e0 * inv;
        sas0[tid] = e0 * inv; sas1[tid] = e1 * inv;
    }
    __syncthreads();
    {
        const int f = tid & 255;
        const int which = tid >> 8;
        const float* sv = which ? sas1 : sas0;
        float acc = 0.f;
        #pragma unroll
        for (int i = 0; i < 16; ++i)
            acc += sv[i] * bf2f(Ah[i * 264 + f]);
        float* gfc = gfr + (blockIdx.x & 3) * 512;
        atomicAdd(&gfc[which * 256 + f], acc);
    }
}

// ===== newadj + last-block finalize (512-block ticket) =====
__global__ __launch_bounds__(256) void newadj_fin(
    const int* __restrict__ src, const int* __restrict__ dst,
    const float* __restrict__ assignp, float* __restrict__ napart,
    int* __restrict__ cntt, const float* __restrict__ gfr,
    float* __restrict__ out) {
    __shared__ float red[4][3];
    __shared__ int sticket;
    const int tid = threadIdx.x;
    const int b = blockIdx.x;
    const int lane = tid & 63;
    const int wave = tid >> 6;

    float ss = 0.f, sd = 0.f, ssd = 0.f;
    {
        int g = (b * 256 + tid) * 4;
        int4 sv = *(const int4*)&src[g];
        int4 dv = *(const int4*)&dst[g];
        float s0 = assignp[sv.x], s1 = assignp[sv.y];
        float s2 = assignp[sv.z], s3 = assignp[sv.w];
        float d0 = assignp[dv.x], d1 = assignp[dv.y];
        float d2 = assignp[dv.z], d3 = assignp[dv.w];
        ss = s0 + s1 + s2 + s3;
        sd = d0 + d1 + d2 + d3;
        ssd = s0 * d0 + s1 * d1 + s2 * d2 + s3 * d3;
    }
    #pragma unroll
    for (int off = 32; off; off >>= 1) {
        ss += __shfl_down(ss, off);
        sd += __shfl_down(sd, off);
        ssd += __shfl_down(ssd, off);
    }
    if (lane == 0) {
        red[wave][0] = ssd; red[wave][1] = ss; red[wave][2] = sd;
    }
    __syncthreads();
    if (tid < 3) {
        float v = red[0][tid] + red[1][tid] + red[2][tid] + red[3][tid];
        __hip_atomic_store(&napart[b * 4 + tid], v, __ATOMIC_RELEASE,
                           __HIP_MEMORY_SCOPE_AGENT);
    }
    __syncthreads();
    if (tid == 0)
        sticket = __hip_atomic_fetch_add(cntt, 1, __ATOMIC_ACQ_REL,
                                         __HIP_MEMORY_SCOPE_AGENT);
    __syncthreads();
    if (sticket != NA_GRID - 1) return;

    float acc = 0.f;
    if (wave < 3) {
        for (int i = lane; i < NA_GRID; i += 64)
            acc += __hip_atomic_load(&napart[i * 4 + wave], __ATOMIC_RELAXED,
                                     __HIP_MEMORY_SCOPE_AGENT);
    }
    #pragma unroll
    for (int off = 32; off; off >>= 1) acc += __shfl_down(acc, off);
    __shared__ float na[3];
    if (lane == 0 && wave < 3) na[wave] = acc;
    __syncthreads();
    float g0 = gfr[tid] + gfr[512 + tid] + gfr[1024 + tid] + gfr[1536 + tid];
    float g1 = gfr[256 + tid] + gfr[768 + tid] + gfr[1280 + tid] + gfr[1792 + tid];
    out[tid] = 0.5f * (g0 + g1);
    out[256 + tid] = fminf(fmaxf(g0, -100.f), 100.f);
    out[512 + tid] = fminf(fmaxf(g1, -100.f), 100.f);
    if (tid == 0) {
        float Ssd = na[0], Ss = na[1], Sd = na[2];
        float n00 = Ssd;
        float n01 = Ss - Ssd;
        float n10 = Sd - Ssd;
        float n11 = (float)N_EDGES - Ss - Sd + Ssd;
        float den0 = fmaxf(fabsf(n00) + fabsf(n01), 1e-12f);
        float den1 = fmaxf(fabsf(n10) + fabsf(n11), 1e-12f);
        float x0 = n00 / den0 - 1.0f;
        float x1 = n11 / den1 - 1.0f;
        out[768] = 0.5f * (x0 * x0 + x1 * x1);
    }
}

// ---------------- launch ----------------

extern "C" void kernel_launch(void* const* d_in, const int* in_sizes, int n_in,
                              void* d_out, int out_size, void* d_ws, size_t ws_size,
                              hipStream_t stream) {
    const float* features = (const float*)d_in[0];
    const int* edges = (const int*)d_in[1];
    const int* src = edges;
    const int* dst = edges + N_EDGES;
    const float* W1 = (const float*)d_in[2];
    const float* b1 = (const float*)d_in[3];
    const float* W2 = (const float*)d_in[4];
    const float* b2 = (const float*)d_in[5];
    const float* fc1_w = (const float*)d_in[6];
    const float* fc1_b = (const float*)d_in[7];
    const float* fc2_w = (const float*)d_in[8];
    const float* fc2_b = (const float*)d_in[9];
    float* out = (float*)d_out;

    char* ws = (char*)d_ws;
    auto carve = [&](size_t bytes) {
        void* q = (void*)ws;
        ws += (bytes + 255) & ~(size_t)255;
        return q;
    };
    // contiguous memset region: cur + gfr + cnt_na
    int* cur = (int*)carve(N_NODES * 4);             // 65536 B
    float* gfr = (float*)carve(4 * 512 * 4);         // 8192 B
    int* cnt_na = (int*)carve(256);                  // 256 B
    ushort_t* col = (ushort_t*)carve((size_t)N_NODES * DEG_CAP * 2);  // 3.1 MB
    float* assignp = (float*)carve(N_NODES * 4);
    float* napart = (float*)carve(NA_GRID * 4 * 4);
    ushort_t* fc1bf = (ushort_t*)carve(64 * 256 * 2);
    uchar_t* zs8 = (uchar_t*)carve((size_t)(N_NODES + 1) * F_IN);     // 2.1 MB
    ushort_t* W1t = (ushort_t*)carve(256 * 128 * 2);
    ushort_t* W2t = (ushort_t*)carve(256 * 256 * 2);
    uchar_t* bufY8 = (uchar_t*)carve((size_t)(N_NODES + 1) * 256);    // 4.2 MB

    hipMemsetAsync(cur, 0, N_NODES * 4 + 4 * 512 * 4 + 256, stream);

    prep_fill<<<2496, 256, 0, stream>>>(src, dst, W1, W2, fc1_w,
                                        cur, col, W1t, W2t, fc1bf);
    scale_feat<<<2049, 256, 0, stream>>>(features, cur, zs8, bufY8, col);
    fused_layer1<<<N_NODES / 16, 512, 0, stream>>>(
        zs8, cur, col, b1, W1t, W2t, bufY8);
    fused_assign<<<N_NODES / 16, 512, 0, stream>>>(
        bufY8, cur, col, b2, fc1bf, fc1_b, fc2_w, fc2_b, assignp, gfr);
    newadj_fin<<<NA_GRID, 256, 0, stream>>>(src, dst, assignp, napart,
                                            cnt_na, gfr, out);
}